// Round 7
// baseline (814.944 us; speedup 1.0000x reference)
//
#include <hip/hip_runtime.h>
#include <cstddef>

// ---------------- problem dims ----------------
#define NF    1024
#define NSEQ  4096
#define NB    4
#define NROWS (NB*NSEQ)      // 16384
#define NADA  6144
#define NHID  4096
#define NST   64
#define NCH   128            // dir(2) * state(64) complex channels
#define LCH   64             // scan chunk length
#define NCHUNK (NSEQ/LCH)    // 64
#define LDA   1280           // Acat leading dim (256 xs + 1024 h)

typedef __bf16 bf16x8 __attribute__((ext_vector_type(8)));
typedef float f32x4 __attribute__((ext_vector_type(4)));
typedef float f32x16 __attribute__((ext_vector_type(16)));

#define AS1 __attribute__((address_space(1)))
#define AS3 __attribute__((address_space(3)))

__device__ __forceinline__ unsigned short f2bf(float x) {
  union { float f; unsigned int u; } v; v.f = x;
  unsigned int r = v.u + 0x7fffu + ((v.u >> 16) & 1u);
  return (unsigned short)(r >> 16);
}

// gelu(x) = 0.5x(1+tanh(u)) == x*sigmoid(2u); fast exp (v_exp_f32)
__device__ __forceinline__ float gelu_fast(float x) {
  float u2 = 1.5957691216057308f*(x + 0.044715f*x*x*x);
  return x / (1.f + __expf(-u2));
}

// ============ 16x16x32 core (64x128 tile, 1x4 waves), two-panel BK=64 ======
template<int TM, int TN, int WM, int WN>
__device__ __forceinline__ void mfma_core(
    const unsigned short* __restrict__ A, int lda,
    const unsigned short* __restrict__ Bt, int ldb,
    int K, int row0, int col0, unsigned short* lds, f32x4* acc)
{
  constexpr int MI = TM/(16*WM), NJ = TN/(16*WN);
  const int tid  = threadIdx.x;
  const int wave = tid >> 6, lane = tid & 63;
  const int wm = wave % WM, wn = wave / WM;
  const int sr = lane >> 2;
  const int sc = (lane & 3) << 3;
  const int fr = lane & 15, fq = lane >> 4;
  unsigned short* sA = lds;             // 2 panels [TM][32]
  unsigned short* sB = lds + 2*TM*32;   // 2 panels [TN][32]
  const unsigned short* a0 = A + (size_t)row0*lda;
  const unsigned short* b0 = Bt + (size_t)col0*ldb;
  for (int k0 = 0; k0 < K; k0 += 64) {
#pragma unroll
    for (int p = 0; p < 2; ++p) {
      int kk = k0 + p*32;
#pragma unroll
      for (int s = 0; s < TM/64; ++s) {
        int u = s*4 + wave;
        __builtin_amdgcn_global_load_lds(
            (const AS1 void*)(a0 + (size_t)(u*16 + sr)*lda + kk + sc),
            (AS3 void*)(sA + p*TM*32 + u*512), 16, 0, 0);
      }
#pragma unroll
      for (int s = 0; s < TN/64; ++s) {
        int u = s*4 + wave;
        __builtin_amdgcn_global_load_lds(
            (const AS1 void*)(b0 + (size_t)(u*16 + sr)*ldb + kk + sc),
            (AS3 void*)(sB + p*TN*32 + u*512), 16, 0, 0);
      }
    }
    __syncthreads();
#pragma unroll
    for (int p = 0; p < 2; ++p) {
      bf16x8 af[MI], bv[NJ];
#pragma unroll
      for (int i = 0; i < MI; ++i)
        af[i] = *(const bf16x8*)(sA + p*TM*32 + (wm*(MI*16) + i*16 + fr)*32 + fq*8);
#pragma unroll
      for (int j = 0; j < NJ; ++j)
        bv[j] = *(const bf16x8*)(sB + p*TN*32 + (wn*(NJ*16) + j*16 + fr)*32 + fq*8);
#pragma unroll
      for (int i = 0; i < MI; ++i)
#pragma unroll
        for (int j = 0; j < NJ; ++j)
          acc[i*NJ+j] = __builtin_amdgcn_mfma_f32_16x16x32_bf16(af[i], bv[j], acc[i*NJ+j], 0, 0, 0);
    }
    __syncthreads();
  }
}

// ============ 32x32x16 core (128x128 tile, 2x2 waves), two-panel BK=64 =====
// A frag: m=lane&31, k=(lane>>5)*8+j (contiguous 8 k). B (from Bt) same.
// Halves ds_read + MFMA inst count vs 16x16x32 at equal FLOPs (m119: 2495 TF).
__device__ __forceinline__ void mfma_core32(
    const unsigned short* __restrict__ A, int lda,
    const unsigned short* __restrict__ Bt, int ldb,
    int K, int row0, int col0, unsigned short* lds, f32x16* acc)
{
  const int tid  = threadIdx.x;
  const int wave = tid >> 6, lane = tid & 63;
  const int wm = wave & 1, wn = wave >> 1;
  const int sr = lane >> 2;
  const int sc = (lane & 3) << 3;
  const int m32 = lane & 31, kh = (lane >> 5) << 3;   // 0 or 8
  unsigned short* sA = lds;             // 2 panels [128][32]
  unsigned short* sB = lds + 2*128*32;  // 2 panels [128][32]
  const unsigned short* a0 = A + (size_t)row0*lda;
  const unsigned short* b0 = Bt + (size_t)col0*ldb;
  for (int k0 = 0; k0 < K; k0 += 64) {
#pragma unroll
    for (int p = 0; p < 2; ++p) {
      int kk = k0 + p*32;
#pragma unroll
      for (int s = 0; s < 2; ++s) {
        int u = s*4 + wave;
        __builtin_amdgcn_global_load_lds(
            (const AS1 void*)(a0 + (size_t)(u*16 + sr)*lda + kk + sc),
            (AS3 void*)(sA + p*4096 + u*512), 16, 0, 0);
        __builtin_amdgcn_global_load_lds(
            (const AS1 void*)(b0 + (size_t)(u*16 + sr)*ldb + kk + sc),
            (AS3 void*)(sB + p*4096 + u*512), 16, 0, 0);
      }
    }
    __syncthreads();
#pragma unroll
    for (int p = 0; p < 2; ++p)
#pragma unroll
      for (int ks = 0; ks < 2; ++ks) {
        bf16x8 af[2], bv[2];
#pragma unroll
        for (int i = 0; i < 2; ++i)
          af[i] = *(const bf16x8*)(sA + p*4096 + (wm*64 + i*32 + m32)*32 + ks*16 + kh);
#pragma unroll
        for (int j = 0; j < 2; ++j)
          bv[j] = *(const bf16x8*)(sB + p*4096 + (wn*64 + j*32 + m32)*32 + ks*16 + kh);
#pragma unroll
        for (int i = 0; i < 2; ++i)
#pragma unroll
          for (int j = 0; j < 2; ++j)
            acc[i*2+j] = __builtin_amdgcn_mfma_f32_32x32x16_bf16(af[i], bv[j], acc[i*2+j], 0, 0, 0);
      }
    __syncthreads();
  }
}

#define ACC_INIT(N_) f32x4 acc[N_]; \
  _Pragma("unroll") for (int z_ = 0; z_ < N_; ++z_) acc[z_] = (f32x4){0.f,0.f,0.f,0.f};

#define ACC32_INIT f32x16 acc[4]; \
  _Pragma("unroll") for (int z_ = 0; z_ < 4; ++z_) \
  _Pragma("unroll") for (int q_ = 0; q_ < 16; ++q_) acc[z_][q_] = 0.f;

// 16x16 D mapping (m89): col = n0+(lane&15), row = m0+(lane>>4)*4+reg
#define EPI_LOOP(WM_, MI_, NJ_, body) \
  { const int lane = threadIdx.x & 63, wave = threadIdx.x >> 6; \
    const int wm = wave % WM_, wn = wave / WM_; \
    const int fr = lane & 15, fq = lane >> 4; \
    _Pragma("unroll") for (int i = 0; i < MI_; ++i) \
    _Pragma("unroll") for (int j = 0; j < NJ_; ++j) \
    _Pragma("unroll") for (int r = 0; r < 4; ++r) { \
      int row = row0 + wm*(MI_*16) + i*16 + fq*4 + r; \
      int col = col0 + wn*(NJ_*16) + j*16 + fr; \
      float aval = acc[i*NJ_+j][r]; \
      body; } }

// 32x32 D mapping (m74/m101): col = n0+(lane&31), row = m0+(reg&3)+8*(reg>>2)+4*(lane>>5)
#define EPI32_LOOP(body) \
  { const int lane = threadIdx.x & 63, wave = threadIdx.x >> 6; \
    const int wm = wave & 1, wn = wave >> 1; \
    const int c5 = lane & 31, rh = (lane >> 5) * 4; \
    _Pragma("unroll") for (int i = 0; i < 2; ++i) \
    _Pragma("unroll") for (int j = 0; j < 2; ++j) \
    _Pragma("unroll") for (int g_ = 0; g_ < 16; ++g_) { \
      int row = row0 + wm*64 + i*32 + (g_&3) + 8*(g_>>2) + rh; \
      int col = col0 + wn*64 + j*32 + c5; \
      float aval = acc[i*2+j][g_]; \
      body; } }

// Bu GEMM fused with scan phase A: 64x128 tile = one scan chunk x 64 complex ch.
__global__ __launch_bounds__(256, 4) void k_mm_bu_scan(
    const unsigned short* __restrict__ A, const unsigned short* __restrict__ Bt,
    const float* __restrict__ Abar, float* __restrict__ Bu, float* __restrict__ P)
{
  __shared__ __align__(16) char smem[64*128*4];            // 32 KB (staging needs 24 KB)
  unsigned short* lds = (unsigned short*)smem;
  float* sbuf = (float*)smem;
  ACC_INIT(8)
  int row0 = blockIdx.x*64, col0 = blockIdx.y*128;
  mfma_core<64,128,1,4>(A, LDA, Bt, 1024, 1024, row0, col0, lds, acc);
  { const int lane = threadIdx.x & 63, wave = threadIdx.x >> 6;
    const int fr = lane & 15, fq = lane >> 4;
#pragma unroll
    for (int i = 0; i < 4; ++i)
#pragma unroll
      for (int j = 0; j < 2; ++j)
#pragma unroll
        for (int r = 0; r < 4; ++r) {
          int rl = i*16 + fq*4 + r;
          int cl = wave*32 + j*16 + fr;
          sbuf[rl*128 + cl] = acc[i*2+j][r];
        }
  }
  __syncthreads();
  int tid = threadIdx.x;
  if (tid < 64) {
    int ch = (col0 >> 1) + tid;
    int d = ch >> 6;
    float2 Ae = ((const float2*)Abar)[ch];
    float sr_ = 0.f, si_ = 0.f;
    for (int jj = 0; jj < LCH; ++jj) {
      int rl = d ? (LCH-1 - jj) : jj;
      float re = sbuf[rl*128 + 2*tid];
      float im = sbuf[rl*128 + 2*tid + 1];
      float nr = Ae.x*sr_ - Ae.y*si_ + re;
      float ni = Ae.x*si_ + Ae.y*sr_ + im;
      sr_ = nr; si_ = ni;
      sbuf[rl*128 + 2*tid]     = sr_;
      sbuf[rl*128 + 2*tid + 1] = si_;
    }
    int bc = row0 >> 6;
    ((float2*)P)[(size_t)bc*NCH + ch] = make_float2(sr_, si_);
  }
  __syncthreads();
  for (int e = tid; e < 64*32; e += 256) {
    int r = e >> 5, q = (e & 31) << 2;
    *(float4*)(Bu + (size_t)(row0 + r)*(2*NCH) + col0 + q) = *(float4*)(sbuf + r*128 + q);
  }
}

// G GEMM: Ccat[256][2048] @ Wot^T -> Bcat cols 0..255 (transposed store)
__global__ __launch_bounds__(256, 4) void k_mm_g(const unsigned short* __restrict__ A,
                                                 const unsigned short* __restrict__ Bt,
                                                 unsigned short* __restrict__ Bcat) {
  __shared__ __align__(16) unsigned short lds[2*(64+128)*32];
  ACC_INIT(8)
  int row0 = blockIdx.x*64, col0 = blockIdx.y*128;
  mfma_core<64,128,1,4>(A, 2048, Bt, 2048, 2048, row0, col0, lds, acc);
  EPI_LOOP(1, 4, 2, Bcat[(size_t)col*LDA + row] = f2bf(aval); )
}

// proj: out = x + g1 * (Acat@Bcat^T + outb); 128x128 tile, 32x32 MFMA
__global__ __launch_bounds__(256, 4) void k_mm_proj(const unsigned short* __restrict__ A,
                                                    const unsigned short* __restrict__ Bt,
                                                    const float* __restrict__ x,
                                                    const float* __restrict__ ada,
                                                    const float* __restrict__ outb,
                                                    float* __restrict__ outp) {
  __shared__ __align__(16) unsigned short lds[2*2*128*32];
  ACC32_INIT
  int row0 = blockIdx.x*128, col0 = blockIdx.y*128;
  mfma_core32(A, LDA, Bt, LDA, LDA, row0, col0, lds, acc);
  EPI32_LOOP(
    const float* g1 = ada + (size_t)(row >> 12)*NADA + 2*NF;
    outp[(size_t)row*NF + col] = x[(size_t)row*NF + col] + g1[col]*(aval + outb[col]); )
}

// mlp1: mid = bf16(gelu(h2@W1t^T + b1)); 128x128 tile, 32x32 MFMA
__global__ __launch_bounds__(256, 4) void k_mm_mlp1(const unsigned short* __restrict__ A,
                                                    const unsigned short* __restrict__ Bt,
                                                    const float* __restrict__ b1,
                                                    unsigned short* __restrict__ mid) {
  __shared__ __align__(16) unsigned short lds[2*2*128*32];
  ACC32_INIT
  int row0 = blockIdx.x*128, col0 = blockIdx.y*128;
  mfma_core32(A, LDA, Bt, 1024, 1024, row0, col0, lds, acc);
  EPI32_LOOP( mid[(size_t)row*NHID + col] = f2bf(gelu_fast(aval + b1[col])); )
}

// mlp2: out += g2 * (mid@W2t^T + b2); 128x128 tile, 32x32 MFMA
__global__ __launch_bounds__(256, 4) void k_mm_mlp2(const unsigned short* __restrict__ A,
                                                    const unsigned short* __restrict__ Bt,
                                                    const float* __restrict__ b2,
                                                    const float* __restrict__ ada,
                                                    float* __restrict__ outp, int row_off) {
  __shared__ __align__(16) unsigned short lds[2*2*128*32];
  ACC32_INIT
  int row0 = blockIdx.x*128, col0 = blockIdx.y*128;
  mfma_core32(A, NHID, Bt, NHID, NHID, row0, col0, lds, acc);
  EPI32_LOOP(
    int rg = row_off + row;
    const float* g2 = ada + (size_t)(rg >> 12)*NADA + 5*NF;
    outp[(size_t)rg*NF + col] += g2[col]*(aval + b2[col]); )
}

// ---------------- small kernels ----------------
__global__ __launch_bounds__(256) void k_ada1(const float* __restrict__ cond, const float* __restrict__ adaW,
                                              float* __restrict__ part) {
  int j = blockIdx.x*256 + threadIdx.x;
  int b = blockIdx.y, z = blockIdx.z;
  float acc = 0.f;
  const float* s = cond + b*NF;
  int k0 = z*128;
  for (int k = k0; k < k0+128; ++k) {
    float c = s[k];
    acc += (c / (1.f + __expf(-c))) * adaW[(size_t)k*NADA + j];
  }
  part[((size_t)(z*NB + b))*NADA + j] = acc;
}

__global__ __launch_bounds__(256) void k_ada2(const float* __restrict__ part, const float* __restrict__ adab,
                                              float* __restrict__ ada) {
  int j = blockIdx.x*256 + threadIdx.x;
  int b = blockIdx.y;
  float acc = adab[j];
#pragma unroll
  for (int z = 0; z < 8; ++z) acc += part[((size_t)(z*NB + b))*NADA + j];
  ada[(size_t)b*NADA + j] = acc;
}

__global__ __launch_bounds__(64) void k_param(
    const float* __restrict__ lAf, const float* __restrict__ Aif, const float* __restrict__ ldtf,
    const float* __restrict__ lAb, const float* __restrict__ Aib, const float* __restrict__ ldtb,
    float* __restrict__ Abar, float* __restrict__ coef, float* __restrict__ AbarL, float* __restrict__ Apow)
{
  int d = blockIdx.x, n = threadIdx.x;
  const float* lA  = d ? lAb  : lAf;
  const float* Ai  = d ? Aib  : Aif;
  const float* ldt = d ? ldtb : ldtf;
  float dt  = expf(ldt[n]);
  float Are = -expf(lA[n]);
  float Aim = Ai[n];
  float ar = Are*dt, ai = Aim*dt;
  float m = expf(ar);
  float Abr = m*cosf(ai), Abi = m*sinf(ai);
  int t = d*NST + n;
  Abar[2*t] = Abr; Abar[2*t+1] = Abi;
  float cr = Abr - 1.f, ci = Abi;
  float dr = Are + 1e-8f, di = Aim;
  float den = dr*dr + di*di;
  coef[2*t]   = (cr*dr + ci*di)/den;
  coef[2*t+1] = (ci*dr - cr*di)/den;
  for (int j = 0; j < LCH; ++j) {
    float p = (float)(j+1);
    float mp = expf(ar*p);
    Apow[(size_t)(t*LCH + j)*2 + 0] = mp*cosf(ai*p);
    Apow[(size_t)(t*LCH + j)*2 + 1] = mp*sinf(ai*p);
  }
  float mL = expf(ar*64.f);
  AbarL[2*t] = mL*cosf(ai*64.f); AbarL[2*t+1] = mL*sinf(ai*64.f);
}

// merged: Bmat_t (blocks 0..511) + Ccat (blocks 512..2559)
__global__ __launch_bounds__(256) void k_tabs(
    const float* __restrict__ Brf, const float* __restrict__ Bif,
    const float* __restrict__ Brb, const float* __restrict__ Bib,
    const float* __restrict__ coef, unsigned short* __restrict__ Bmat_t,
    const float* __restrict__ Crf, const float* __restrict__ Cif,
    const float* __restrict__ Crb, const float* __restrict__ Cib,
    unsigned short* __restrict__ Ccat)
{
  if (blockIdx.x < 512) {
    int id = blockIdx.x*256 + threadIdx.x;
    int f = id & (NF-1), c = id >> 10;
    int d = c >> 6, n = c & 63;
    const float* Br = d ? Brb : Brf;
    const float* Bi = d ? Bib : Bif;
    float br = Br[(size_t)n*NF + f], bi = Bi[(size_t)n*NF + f];
    float crr = coef[2*c], cii = coef[2*c+1];
    Bmat_t[(size_t)(2*c)*NF + f]   = f2bf(crr*br - cii*bi);
    Bmat_t[(size_t)(2*c+1)*NF + f] = f2bf(crr*bi + cii*br);
  } else {
    int id = (blockIdx.x - 512)*256 + threadIdx.x;
    int fp = id & 2047, r = id >> 11;
    int p = r & 1, c = r >> 1, d = c >> 6, n = c & 63;
    int fd = fp >> 10, f = fp & 1023;
    float v = 0.f;
    if (fd == d) {
      const float* Cr = d ? Crb : Crf;
      const float* Ci = d ? Cib : Cif;
      v = p ? -Ci[(size_t)f*NST + n] : Cr[(size_t)f*NST + n];
    }
    Ccat[id] = f2bf(v);
  }
}

__device__ __forceinline__ void tcvt_tile(const float* __restrict__ src, int C,
                                          unsigned short* __restrict__ dst, int ldd,
                                          int r0, int c0, float* t) {
  for (int rr = threadIdx.y; rr < 32; rr += 8)
    t[rr*33 + threadIdx.x] = src[(size_t)(r0+rr)*C + c0 + threadIdx.x];
  __syncthreads();
  for (int rr = threadIdx.y; rr < 32; rr += 8)
    dst[(size_t)(c0+rr)*ldd + r0 + threadIdx.x] = f2bf(t[threadIdx.x*33 + rr]);
}

// merged weight prep: W1t | W2t | Wot | WD->Bcat
__global__ void k_wprep(const float* __restrict__ W1, const float* __restrict__ W2,
                        const float* __restrict__ outW,
                        const float* __restrict__ Df, const float* __restrict__ Db,
                        unsigned short* __restrict__ W1t, unsigned short* __restrict__ W2t,
                        unsigned short* __restrict__ Wot, unsigned short* __restrict__ BcatWD) {
  __shared__ float t1[32*33], t2[32*33];
  __shared__ float df[32], db[32];
  int g = blockIdx.x;
  if (g < 4096) {
    int c0 = (g & 127)*32, r0 = (g >> 7)*32;
    tcvt_tile(W1, NHID, W1t, NF, r0, c0, t1);
  } else if (g < 8192) {
    int g2 = g - 4096;
    int c0 = (g2 & 31)*32, r0 = (g2 >> 5)*32;
    tcvt_tile(W2, NF, W2t, NHID, r0, c0, t1);
  } else if (g < 10240) {
    int g3 = g - 8192;
    int c0 = (g3 & 31)*32, r0 = (g3 >> 5)*32;
    tcvt_tile(outW, NF, Wot, 2048, r0, c0, t1);
  } else {
    int g4 = g - 10240;
    int fo0 = (g4 & 31)*32, f0 = (g4 >> 5)*32;
    for (int rr = threadIdx.y; rr < 32; rr += 8) {
      t1[rr*33 + threadIdx.x] = outW[(size_t)(f0+rr)*NF + fo0 + threadIdx.x];
      t2[rr*33 + threadIdx.x] = outW[(size_t)(NF+f0+rr)*NF + fo0 + threadIdx.x];
    }
    if (threadIdx.y == 0) { df[threadIdx.x] = Df[f0+threadIdx.x]; db[threadIdx.x] = Db[f0+threadIdx.x]; }
    __syncthreads();
    for (int rr = threadIdx.y; rr < 32; rr += 8)
      BcatWD[(size_t)(fo0+rr)*LDA + f0 + threadIdx.x] =
          f2bf(df[threadIdx.x]*t1[threadIdx.x*33 + rr] + db[threadIdx.x]*t2[threadIdx.x*33 + rr]);
  }
}

// LayerNorm + AdaLN modulate, bf16 output into Acat region (ld = LDA)
__global__ __launch_bounds__(256) void k_ln_mod_bf(const float* __restrict__ xin, const float* __restrict__ ada,
                                                   int sh_off, int sc_off, unsigned short* __restrict__ outp) {
  const int row = blockIdx.x;
  const int b = row >> 12;
  const int tid = threadIdx.x;
  float4 v = ((const float4*)(xin + (size_t)row*NF))[tid];
  float s1 = v.x+v.y+v.z+v.w;
  float s2 = v.x*v.x + v.y*v.y + v.z*v.z + v.w*v.w;
  for (int off = 32; off > 0; off >>= 1) { s1 += __shfl_down(s1, off); s2 += __shfl_down(s2, off); }
  __shared__ float r1[4], r2[4];
  if ((tid & 63) == 0) { r1[tid>>6] = s1; r2[tid>>6] = s2; }
  __syncthreads();
  float S1 = r1[0]+r1[1]+r1[2]+r1[3];
  float S2 = r2[0]+r2[1]+r2[2]+r2[3];
  float mean = S1 * (1.0f/NF);
  float var  = S2 * (1.0f/NF) - mean*mean;
  float inv  = rsqrtf(var + 1e-5f);
  const float* arow = ada + (size_t)b*NADA;
  int f = tid << 2;
  ushort4 r;
  r.x = f2bf((v.x - mean)*inv*(1.f + arow[sc_off + f+0]) + arow[sh_off + f+0]);
  r.y = f2bf((v.y - mean)*inv*(1.f + arow[sc_off + f+1]) + arow[sh_off + f+1]);
  r.z = f2bf((v.z - mean)*inv*(1.f + arow[sc_off + f+2]) + arow[sh_off + f+2]);
  r.w = f2bf((v.w - mean)*inv*(1.f + arow[sc_off + f+3]) + arow[sh_off + f+3]);
  *(ushort4*)(outp + (size_t)row*LDA + f) = r;
}

// scan phase B: sequential combine of chunk carries
__global__ __launch_bounds__(512) void k_scanB(const float* __restrict__ P, const float* __restrict__ AbarL,
                                               float* __restrict__ carry) {
  int t = threadIdx.x & (NCH-1);
  int b = threadIdx.x >> 7;
  int d = t >> 6;
  float2 AL = ((const float2*)AbarL)[t];
  float sr = 0.f, si = 0.f;
  if (d == 0) {
    for (int c = 0; c < NCHUNK; ++c) {
      ((float2*)carry)[((size_t)b*NCHUNK + c)*NCH + t] = make_float2(sr, si);
      float2 p = ((const float2*)P)[((size_t)b*NCHUNK + c)*NCH + t];
      float nr = AL.x*sr - AL.y*si + p.x;
      float ni = AL.x*si + AL.y*sr + p.y;
      sr = nr; si = ni;
    }
  } else {
    for (int c = NCHUNK-1; c >= 0; --c) {
      ((float2*)carry)[((size_t)b*NCHUNK + c)*NCH + t] = make_float2(sr, si);
      float2 p = ((const float2*)P)[((size_t)b*NCHUNK + c)*NCH + t];
      float nr = AL.x*sr - AL.y*si + p.x;
      float ni = AL.x*si + AL.y*sr + p.y;
      sr = nr; si = ni;
    }
  }
}

// scan phase C fused with bf16 convert: Acat cols 0..255 <- local + A^(tau+1)*carry
__global__ __launch_bounds__(128) void k_scanC(const float* __restrict__ Bu, const float* __restrict__ Apow,
                                               const float* __restrict__ carry,
                                               unsigned short* __restrict__ Acat) {
  int t = threadIdx.x;
  int bc = blockIdx.x;
  int b = bc >> 6, c = bc & 63;
  int d = t >> 6;
  float2 E = ((const float2*)carry)[(size_t)bc*NCH + t];
  const float2* Ap = ((const float2*)Apow) + (size_t)t*LCH;
  size_t base = ((size_t)b*NSEQ)*(2*NCH);
  for (int j = 0; j < LCH; ++j) {
    int s = c*LCH + j;
    int tau = d ? (LCH-1 - j) : j;
    float2 ap = Ap[tau];
    float2 v = *((const float2*)(Bu + base + (size_t)s*(2*NCH)) + t);
    v.x += ap.x*E.x - ap.y*E.y;
    v.y += ap.x*E.y + ap.y*E.x;
    ushort2 o; o.x = f2bf(v.x); o.y = f2bf(v.y);
    *(ushort2*)(Acat + (size_t)(b*NSEQ + s)*LDA + 2*t) = o;
  }
}

// ---------------- launcher ----------------
extern "C" void kernel_launch(void* const* d_in, const int* in_sizes, int n_in,
                              void* d_out, int out_size, void* d_ws, size_t ws_size,
                              hipStream_t stream) {
  const bool sig = (in_sizes[4] == 64);
  const float* x    = (const float*)d_in[0];
  const float* cond = (const float*)d_in[1];
  const float* adaW = (const float*)d_in[2];
  const float* adab = (const float*)d_in[3];
  const int fwd0 = sig ? 4 : 11;
  const int bwd0 = sig ? 12 : 19;
  const float* outW = (const float*)d_in[sig ? 20 : 4];
  const float* outb = (const float*)d_in[sig ? 21 : 5];
  const float* W1   = (const float*)d_in[sig ? 22 : 6];
  const float* b1   = (const float*)d_in[sig ? 23 : 7];
  const float* W2   = (const float*)d_in[sig ? 24 : 8];
  const float* b2   = (const float*)d_in[sig ? 25 : 9];
  const float* lAf  = (const float*)d_in[fwd0+0];
  const float* Aif  = (const float*)d_in[fwd0+1];
  const float* Brf  = (const float*)d_in[fwd0+2];
  const float* Bif  = (const float*)d_in[fwd0+3];
  const float* Crf  = (const float*)d_in[fwd0+4];
  const float* Cif  = (const float*)d_in[fwd0+5];
  const float* Df   = (const float*)d_in[fwd0+6];
  const float* ldtf = (const float*)d_in[fwd0+7];
  const float* lAb  = (const float*)d_in[bwd0+0];
  const float* Aib  = (const float*)d_in[bwd0+1];
  const float* Brb  = (const float*)d_in[bwd0+2];
  const float* Bib  = (const float*)d_in[bwd0+3];
  const float* Crb  = (const float*)d_in[bwd0+4];
  const float* Cib  = (const float*)d_in[bwd0+5];
  const float* Db   = (const float*)d_in[bwd0+6];
  const float* ldtb = (const float*)d_in[bwd0+7];
  float* out = (float*)d_out;
  (void)n_in; (void)out_size;

  char* w = (char*)d_ws;
  auto alloc = [&](size_t bytes) { char* p = w; w += (bytes + 255) & ~(size_t)255; return p; };
  unsigned short* Acat   = (unsigned short*)alloc((size_t)NROWS*LDA*2);     // 41.9 MB
  unsigned short* W1t    = (unsigned short*)alloc((size_t)NHID*NF*2);       // 8.4 MB
  unsigned short* W2t    = (unsigned short*)alloc((size_t)NF*NHID*2);       // 8.4 MB
  unsigned short* Wot    = (unsigned short*)alloc((size_t)NF*2048*2);       // 4.2 MB
  unsigned short* Ccat   = (unsigned short*)alloc((size_t)256*2048*2);      // 1.0 MB
  unsigned short* Bmat_t = (unsigned short*)alloc((size_t)2*NCH*NF*2);      // 0.5 MB
  unsigned short* Bcat   = (unsigned short*)alloc((size_t)NF*LDA*2);        // 2.6 MB
  float* bu    = (float*)alloc((size_t)NROWS*2*NCH*4);                      // 16.8 MB
  float* ada   = (float*)alloc((size_t)NB*NADA*4);
  float* part  = (float*)alloc((size_t)8*NB*NADA*4);
  float* Abar  = (float*)alloc(2*NCH*4);
  float* AbarL = (float*)alloc(2*NCH*4);
  float* coef  = (float*)alloc(2*NCH*4);
  float* Apow  = (float*)alloc((size_t)NCH*LCH*2*4);
  float* P     = (float*)alloc((size_t)NB*NCHUNK*NCH*2*4);
  float* carry = (float*)alloc((size_t)NB*NCHUNK*NCH*2*4);
  size_t used = (size_t)(w - (char*)d_ws);
  int mrows = NROWS;
  while (mrows > 4096 && used + (size_t)mrows*NHID*2 > ws_size) mrows >>= 1;
  unsigned short* mid = (unsigned short*)alloc((size_t)mrows*NHID*2);

  k_ada1<<<dim3(NADA/256, NB, 8), 256, 0, stream>>>(cond, adaW, part);
  k_ada2<<<dim3(NADA/256, NB), 256, 0, stream>>>(part, adab, ada);
  k_param<<<2, 64, 0, stream>>>(lAf, Aif, ldtf, lAb, Aib, ldtb, Abar, coef, AbarL, Apow);
  k_tabs<<<2560, 256, 0, stream>>>(Brf, Bif, Brb, Bib, coef, Bmat_t, Crf, Cif, Crb, Cib, Ccat);
  k_wprep<<<11264, dim3(32,8), 0, stream>>>(W1, W2, outW, Df, Db, W1t, W2t, Wot, Bcat + 256);

  k_mm_g<<<dim3(4, NF/128), 256, 0, stream>>>(Ccat, Wot, Bcat);

  k_ln_mod_bf<<<NROWS, 256, 0, stream>>>(x, ada, 0, NF, Acat + 256);

  k_mm_bu_scan<<<dim3(NROWS/64, (2*NCH)/128), 256, 0, stream>>>(Acat + 256, Bmat_t, Abar, bu, P);

  k_scanB<<<1, 512, 0, stream>>>(P, AbarL, carry);
  k_scanC<<<NB*NCHUNK, NCH, 0, stream>>>(bu, Apow, carry, Acat);

  k_mm_proj<<<dim3(NROWS/128, NF/128), 256, 0, stream>>>(Acat, Bcat, x, ada, outb, out);

  k_ln_mod_bf<<<NROWS, 256, 0, stream>>>(out, ada, 3*NF, 4*NF, Acat + 256);

  for (int r0 = 0; r0 < NROWS; r0 += mrows) {
    k_mm_mlp1<<<dim3(mrows/128, NHID/128), 256, 0, stream>>>(Acat + 256 + (size_t)r0*LDA, W1t, b1, mid);
    k_mm_mlp2<<<dim3(mrows/128, NF/128), 256, 0, stream>>>(mid, W2t, b2, ada, out, r0);
  }
}